// Round 3
// baseline (3475.319 us; speedup 1.0000x reference)
//
#include <hip/hip_runtime.h>

typedef unsigned int uint;
typedef unsigned short ushort_t;

#define NB 512      // batch
#define NK 1152     // input capsules
#define ND 8        // in dim
#define NU 16       // out dim
#define NJ 10       // output capsules
#define NPH 30      // routing phases (NJ * 3)
#define EPSQ 1e-7f

#define KT 36       // k per tile
#define KCN 32      // k chunks; kc = blockIdx&31 -> XCD = kc%8
#define BT 16       // b per tile
#define BGN 32      // b groups
#define XPH 296     // x tile pitch per b, in bf16 elems (288 + 8 pad -> 2-way banks)
#define WPH 136     // w tile pitch per k, in bf16 elems (128 + 8 pad -> 2-way banks)
#define SREDP 20    // part cross-wave reduce pitch (floats)
#define SVP 20      // agp sv pitch (floats, 16B-stride-aligned)
#define BLP 12      // bl_lds row pitch (floats)

// ws layout (floats)
#define OFF_BL 0                        // b_logits [NK][NJ]      11520   (fallback only)
#define OFF_S  11520                    // s [NPH][NB][NU]        245760  (fallback only)
#define OFF_XB 257280                   // Xb bf16 [NB][NK][ND]   (2359296 floats)
#define OFF_WTB (OFF_XB + (NB*NK*ND)/2) // WTb bf16 [NJ][NK][NU][ND] (737280 floats)
#define OFF_CNT (OFF_WTB + (NJ*NK*NU*ND)/2) // barrier counters (ints)
#define NCNT (NPH * (BGN + KCN))        // 1920 ints
#define OFF_SPART (OFF_CNT + NCNT)      // s partials [2][KCN][NB][NU]  524288 floats
#define OFF_AGP (OFF_SPART + 2*KCN*NB*NU) // agree partials [2][BGN][NK] 73728 floats
// total ~16 MB << ws

// fp32 -> bf16 RNE (values are finite/normal here)
__device__ __forceinline__ ushort_t b16(float f) {
  uint u = __float_as_uint(f);
  return (ushort_t)((u + 0x7fffu + ((u >> 16) & 1u)) >> 16);
}
// unpack 8 bf16 (uint4) -> 8 fp32
__device__ __forceinline__ void up8(const uint4 v, float* f) {
  f[0] = __uint_as_float(v.x << 16); f[1] = __uint_as_float(v.x & 0xffff0000u);
  f[2] = __uint_as_float(v.y << 16); f[3] = __uint_as_float(v.y & 0xffff0000u);
  f[4] = __uint_as_float(v.z << 16); f[5] = __uint_as_float(v.z & 0xffff0000u);
  f[6] = __uint_as_float(v.w << 16); f[7] = __uint_as_float(v.w & 0xffff0000u);
}
__device__ __forceinline__ float dot8(const float* a, const float* b) {
  return a[0]*b[0] + a[1]*b[1] + a[2]*b[2] + a[3]*b[3] +
         a[4]*b[4] + a[5]*b[5] + a[6]*b[6] + a[7]*b[7];
}

__device__ __forceinline__ float cohload(const float* p) {
  return __hip_atomic_load(p, __ATOMIC_RELAXED, __HIP_MEMORY_SCOPE_AGENT);
}
__device__ __forceinline__ void cohstore(float* p, float v) {
  __hip_atomic_store(p, v, __ATOMIC_RELAXED, __HIP_MEMORY_SCOPE_AGENT);
}

// --- 32-block partial barrier, fully relaxed -------------------------------
// All cross-block data moves through agent-scope atomic stores/loads, which
// are serviced at the LLC coherence point (bypass the non-coherent per-XCD
// L2s). Producer: __syncthreads() emits s_waitcnt vmcnt(0) -> every data
// store of the block is ACK'd at the LLC before thread 0's counter add.
// Consumer: poll result gates __syncthreads() (also a compiler barrier), so
// post-barrier coherent loads observe committed data. No acquire/release ->
// no buffer_inv storms (round-1 lesson); no fp32 RMW -> no CAS storms
// (round-2 lesson).
__device__ __forceinline__ void gbar_arrive(int* c) {
  __syncthreads();
  if (threadIdx.x == 0)
    __hip_atomic_fetch_add(c, 1, __ATOMIC_RELAXED, __HIP_MEMORY_SCOPE_AGENT);
}
__device__ __forceinline__ void gbar_wait(int* c) {
  if (threadIdx.x == 0) {
    int it = 0;
    while (__hip_atomic_load(c, __ATOMIC_RELAXED, __HIP_MEMORY_SCOPE_AGENT) < 32) {
      __builtin_amdgcn_s_sleep(1);
      if (++it > (1 << 22)) break;  // safety valve: wrong-answer beats hang
    }
  }
  __syncthreads();
}
__device__ __forceinline__ void gbar(int* c) { gbar_arrive(c); gbar_wait(c); }

// ---------------------------------------------------------------------------
// init: zero bl + s + barrier counters; build Xb[b][k][d] (bf16) and
// WTb[j][k][u][d] (bf16)
// ---------------------------------------------------------------------------
__global__ __launch_bounds__(256) void caps_init(const float* __restrict__ x,
                                                 const float* __restrict__ W,
                                                 float* __restrict__ bl,
                                                 float* __restrict__ s,
                                                 ushort_t* __restrict__ Xb,
                                                 ushort_t* __restrict__ WTb,
                                                 int* __restrict__ cnt) {
  const int g = blockIdx.x * 256 + threadIdx.x;
  if (g < NK * NJ) bl[g] = 0.f;
  if (g < NPH * NB * NU) s[g] = 0.f;
  if (g < NCNT) cnt[g] = 0;
  if (g < (NB * NK * ND) / 8) {  // 589824 groups of 8
    const float4* xp = (const float4*)x + (size_t)g * 2;
    const float4 a = xp[0], b = xp[1];
    uint4 o;
    o.x = (uint)b16(a.x) | ((uint)b16(a.y) << 16);
    o.y = (uint)b16(a.z) | ((uint)b16(a.w) << 16);
    o.z = (uint)b16(b.x) | ((uint)b16(b.y) << 16);
    o.w = (uint)b16(b.z) | ((uint)b16(b.w) << 16);
    ((uint4*)Xb)[g] = o;
  }
  if (g < (NJ * NK * NU * ND) / 8) {  // 184320 groups: (j,k,u) rows of 8 d
    const int u = g & 15;
    const int k = (g >> 4) % NK;
    const int j = g / (NK * NU);
    const float* wp = W + ((size_t)(j * NK + k) * ND) * NU + u;  // d-stride NU
    uint4 o;
    o.x = (uint)b16(wp[0])  | ((uint)b16(wp[16]) << 16);
    o.y = (uint)b16(wp[32]) | ((uint)b16(wp[48]) << 16);
    o.z = (uint)b16(wp[64]) | ((uint)b16(wp[80]) << 16);
    o.w = (uint)b16(wp[96]) | ((uint)b16(wp[112]) << 16);
    ((uint4*)WTb)[g] = o;
  }
}

// ---------------------------------------------------------------------------
// caps_main: persistent cooperative kernel, contention-free version.
// 1024 blocks (4/CU); block (kc,bgi) owns a 16b x 36k tile. X staged to LDS
// once; W once per j. bl lives ONLY in LDS (private per-kc copy, redundantly
// maintained by all 32 bgi-peers). Cross-block reductions go through
// per-phase partial buffers written with relaxed agent-scope stores (no RMW).
// Phase n=(j,t):
//   [stage W if t==0] [wait cb(n-1)] fold ag_part(n-1) into bl_lds ->
//   softmax -> part -> store s_part -> cs barrier -> sum s_part + squash ->
//   agree -> store ag_part -> arrive cb(n).
// ---------------------------------------------------------------------------
__global__ __launch_bounds__(256, 4) void caps_main(
    const ushort_t* __restrict__ Xb, const ushort_t* __restrict__ WTb,
    float* __restrict__ s_part, float* __restrict__ ag_part,
    float* __restrict__ out, int* __restrict__ cs, int* __restrict__ cb) {
  __shared__ __align__(16) ushort_t sxu[BT * XPH];  // 9472 B, persistent
  __shared__ __align__(16) ushort_t swu[KT * WPH];  // 9792 B, per-j
  __shared__ float sc[KT];
  __shared__ float svbuf[BT * SVP];                 // 1280 B
  __shared__ float sred[4 * BT * SREDP];            // 5120 B
  __shared__ float bl_lds[KT * BLP];                // 1728 B, private bl slice
  const int tid = threadIdx.x;
  const int kc = blockIdx.x & (KCN - 1);
  const int bgi = blockIdx.x >> 5;
  const int b0 = bgi * BT;
  const int k0 = kc * KT;

  {  // stage x ONCE: 576 uint4 (one per (b,k))
    const uint4* gx = (const uint4*)Xb + ((size_t)b0 * NK + k0);
    for (int i = tid; i < BT * KT; i += 256) {
      const int b = i / KT, q = i - b * KT;
      *(uint4*)&sxu[b * XPH + q * 8] = gx[(size_t)b * NK + q];
    }
  }
  for (int i = tid; i < KT * BLP; i += 256) bl_lds[i] = 0.f;

  const int w = tid >> 6;
  const int lane = tid & 63;
  const int kq = lane >> 4;
  const int bq = (lane >> 2) & 3;
  const int uq = lane & 3;

  for (int n = 0; n < NPH; ++n) {
    const int j = n / 3;
    const int t = n - 3 * j;
    const int buf = n & 1;
    float* spart_n = s_part + (size_t)buf * KCN * NB * NU;
    float* agp_n = ag_part + (size_t)buf * BGN * NK;

    if (t == 0) {  // stage W for new j (overlaps the cb wait below). Safe:
      // agree(n-1)'s swu reads completed before cb(n-1)-arrive's syncthreads.
      const uint4* gw = (const uint4*)WTb + ((size_t)j * NK + k0) * NU;
      for (int i = tid; i < KT * NU; i += 256) {
        const int k = i >> 4, u = i & 15;
        *(uint4*)&swu[k * WPH + u * 8] = gw[i];
      }
    }
    if (n > 0) {
      gbar_wait(&cb[(size_t)(n - 1) * KCN + kc]);  // ag_part(n-1) ready
      // fold agree partials into private bl copy: bl_lds[k][jprev] += sum_g
      const int jprev = (n - 1) / 3;
      const float* agp_p = ag_part + (size_t)((n - 1) & 1) * BGN * NK;
      for (int idx = tid; idx < KT * BGN; idx += 256) {
        const int k = idx >> 5, g = idx & 31;  // g == lane&31 (aligned)
        float v = cohload(&agp_p[(size_t)g * NK + k0 + k]);
        v += __shfl_xor(v, 1, 64);
        v += __shfl_xor(v, 2, 64);
        v += __shfl_xor(v, 4, 64);
        v += __shfl_xor(v, 8, 64);
        v += __shfl_xor(v, 16, 64);
        if ((lane & 31) == 0) bl_lds[k * BLP + jprev] += v;
      }
      __syncthreads();  // bl_lds visible
    }

    if (tid < KT) {  // softmax of private bl row, column j (pure LDS)
      float r[NJ];
#pragma unroll
      for (int jj = 0; jj < NJ; ++jj) r[jj] = bl_lds[tid * BLP + jj];
      float mx = r[0];
#pragma unroll
      for (int jj = 1; jj < NJ; ++jj) mx = fmaxf(mx, r[jj]);
      float se = 0.f;
#pragma unroll
      for (int jj = 0; jj < NJ; ++jj) se += __expf(r[jj] - mx);
      sc[tid] = __expf(r[j] - mx) / se;
    }
    __syncthreads();  // sc + swu (+ initial sxu) visible

    // ---- part: partial s for this (kc,bgi) tile
    float a[4][4];
#pragma unroll
    for (int i = 0; i < 4; ++i)
#pragma unroll
      for (int m = 0; m < 4; ++m) a[i][m] = 0.f;
#pragma unroll
    for (int it = 0; it < 3; ++it) {
      const int kli = it * 4 + kq;
      if (kli < 9) {
        const int kl = w * 9 + kli;
        const float ck = sc[kl];
        float xd[4][8];
#pragma unroll
        for (int i = 0; i < 4; ++i)
          up8(*(const uint4*)&sxu[(bq * 4 + i) * XPH + kl * 8], xd[i]);
#pragma unroll
        for (int m = 0; m < 4; ++m) {
          float wd[8];
          up8(*(const uint4*)&swu[kl * WPH + (uq * 4 + m) * 8], wd);
#pragma unroll
          for (int i = 0; i < 4; ++i)
            a[i][m] = fmaf(ck, dot8(xd[i], wd), a[i][m]);
        }
      }
    }
#pragma unroll
    for (int i = 0; i < 4; ++i)
#pragma unroll
      for (int m = 0; m < 4; ++m) {
        a[i][m] += __shfl_xor(a[i][m], 16, 64);
        a[i][m] += __shfl_xor(a[i][m], 32, 64);
      }
    if (kq == 0) {
#pragma unroll
      for (int i = 0; i < 4; ++i) {
        const float4 t4 = {a[i][0], a[i][1], a[i][2], a[i][3]};
        *(float4*)&sred[(w * BT + bq * 4 + i) * SREDP + uq * 4] = t4;
      }
    }
    __syncthreads();
    {  // sum 4 waves -> tile partial; coherent store (coalesced, no RMW)
      const int b = tid >> 4, u = tid & 15;
      const float pv =
          sred[(0 * BT + b) * SREDP + u] + sred[(1 * BT + b) * SREDP + u] +
          sred[(2 * BT + b) * SREDP + u] + sred[(3 * BT + b) * SREDP + u];
      cohstore(&spart_n[((size_t)kc * NB + (b0 + b)) * NU + u], pv);
    }
    gbar(&cs[(size_t)n * BGN + bgi]);  // all kc partials for this b-slice

    {  // sum 32 kc partials + squash (redundant across kc-peers, local-only)
      const int b = tid >> 4, u = tid & 15;
      const float* sp = spart_n + (size_t)(b0 + b) * NU + u;
      float sval = 0.f;
#pragma unroll
      for (int g = 0; g < KCN; ++g) sval += cohload(sp + (size_t)g * NB * NU);
      float sq = sval * sval;
      sq += __shfl_xor(sq, 1, 64);
      sq += __shfl_xor(sq, 2, 64);
      sq += __shfl_xor(sq, 4, 64);
      sq += __shfl_xor(sq, 8, 64);
      const float scale = (sq / (1.f + sq)) / (sqrtf(sq) + EPSQ);
      const float vv = scale * sval;
      svbuf[b * SVP + u] = vv;
      if (t == 2 && kc == 0)
        out[((size_t)(b0 + b) * NJ + j) * NU + u] = vv;
    }
    __syncthreads();

    if (n < NPH - 1) {  // agree (column j, same swu); skip at n=29 (dead)
      float4 vf[4];
#pragma unroll
      for (int i = 0; i < 4; ++i)
        vf[i] = *(const float4*)&svbuf[(bq * 4 + i) * SVP + uq * 4];
#pragma unroll
      for (int it = 0; it < 3; ++it) {
        const int kli = it * 4 + kq;
        if (kli < 9) {
          const int kl = w * 9 + kli;
          float xd[4][8];
#pragma unroll
          for (int i = 0; i < 4; ++i)
            up8(*(const uint4*)&sxu[(bq * 4 + i) * XPH + kl * 8], xd[i]);
          float ag = 0.f;
#pragma unroll
          for (int m = 0; m < 4; ++m) {
            float wd[8];
            up8(*(const uint4*)&swu[kl * WPH + (uq * 4 + m) * 8], wd);
#pragma unroll
            for (int i = 0; i < 4; ++i) {
              const float vm = (m == 0) ? vf[i].x
                             : (m == 1) ? vf[i].y
                             : (m == 2) ? vf[i].z : vf[i].w;
              ag = fmaf(vm, dot8(xd[i], wd), ag);
            }
          }
          ag += __shfl_xor(ag, 1, 64);
          ag += __shfl_xor(ag, 2, 64);
          ag += __shfl_xor(ag, 4, 64);
          ag += __shfl_xor(ag, 8, 64);
          if ((lane & 15) == 0)  // block's 16b x 16u sum for k = k0+kl
            cohstore(&agp_n[(size_t)bgi * NK + k0 + kl], ag);
        }
      }
      gbar_arrive(&cb[(size_t)n * KCN + kc]);  // ag partials published
    }
  }
}

// ---------------------------------------------------------------------------
// Fallback path kernels (proven 59-launch version), used only if cooperative
// launch is rejected.
// ---------------------------------------------------------------------------
__global__ __launch_bounds__(256, 4) void caps_part(
    const ushort_t* __restrict__ Xb, const ushort_t* __restrict__ WTb,
    const float* __restrict__ bl, float* __restrict__ sn, int js) {
  __shared__ __align__(16) ushort_t sxu[BT * XPH];
  __shared__ __align__(16) ushort_t swu[KT * WPH];
  __shared__ float sc[KT];
  float* sred = (float*)sxu;
  const int tid = threadIdx.x;
  const int kc = blockIdx.x & (KCN - 1);
  const int bgi = blockIdx.x >> 5;
  const int b0 = bgi * BT;
  const int k0 = kc * KT;
  {
    const uint4* gx = (const uint4*)Xb + ((size_t)b0 * NK + k0);
    for (int i = tid; i < BT * KT; i += 256) {
      const int b = i / KT, q = i - b * KT;
      *(uint4*)&sxu[b * XPH + q * 8] = gx[(size_t)b * NK + q];
    }
  }
  {
    const uint4* gw = (const uint4*)WTb + ((size_t)js * NK + k0) * NU;
    for (int i = tid; i < KT * NU; i += 256) {
      const int k = i >> 4, u = i & 15;
      *(uint4*)&swu[k * WPH + u * 8] = gw[i];
    }
  }
  if (tid < KT) {
    const float* row = bl + (size_t)(k0 + tid) * NJ;
    float r[NJ];
#pragma unroll
    for (int jj = 0; jj < NJ; ++jj) r[jj] = row[jj];
    float mx = r[0];
#pragma unroll
    for (int jj = 1; jj < NJ; ++jj) mx = fmaxf(mx, r[jj]);
    float se = 0.f;
#pragma unroll
    for (int jj = 0; jj < NJ; ++jj) se += __expf(r[jj] - mx);
    sc[tid] = __expf(r[js] - mx) / se;
  }
  __syncthreads();
  const int w = tid >> 6;
  const int lane = tid & 63;
  const int kq = lane >> 4;
  const int bq = (lane >> 2) & 3;
  const int uq = lane & 3;
  float a[4][4];
#pragma unroll
  for (int i = 0; i < 4; ++i)
#pragma unroll
    for (int m = 0; m < 4; ++m) a[i][m] = 0.f;
#pragma unroll
  for (int it = 0; it < 3; ++it) {
    const int kli = it * 4 + kq;
    if (kli < 9) {
      const int kl = w * 9 + kli;
      const float ck = sc[kl];
      float xd[4][8];
#pragma unroll
      for (int i = 0; i < 4; ++i)
        up8(*(const uint4*)&sxu[(bq * 4 + i) * XPH + kl * 8], xd[i]);
#pragma unroll
      for (int m = 0; m < 4; ++m) {
        float wd[8];
        up8(*(const uint4*)&swu[kl * WPH + (uq * 4 + m) * 8], wd);
#pragma unroll
        for (int i = 0; i < 4; ++i)
          a[i][m] = fmaf(ck, dot8(xd[i], wd), a[i][m]);
      }
    }
  }
#pragma unroll
  for (int i = 0; i < 4; ++i)
#pragma unroll
    for (int m = 0; m < 4; ++m) {
      a[i][m] += __shfl_xor(a[i][m], 16, 64);
      a[i][m] += __shfl_xor(a[i][m], 32, 64);
    }
  __syncthreads();
  if (kq == 0) {
#pragma unroll
    for (int i = 0; i < 4; ++i) {
      const float4 t4 = {a[i][0], a[i][1], a[i][2], a[i][3]};
      *(float4*)&sred[(w * BT + bq * 4 + i) * SREDP + uq * 4] = t4;
    }
  }
  __syncthreads();
  {
    const int b = tid >> 4, u = tid & 15;
    const float sv =
        sred[(0 * BT + b) * SREDP + u] + sred[(1 * BT + b) * SREDP + u] +
        sred[(2 * BT + b) * SREDP + u] + sred[(3 * BT + b) * SREDP + u];
    atomicAdd(&sn[(size_t)(b0 + b) * NU + u], sv);
  }
}

__global__ __launch_bounds__(256, 4) void caps_agp(
    const ushort_t* __restrict__ Xb, const ushort_t* __restrict__ WTb,
    const float* __restrict__ sprev, float* __restrict__ bl,
    float* __restrict__ out, int ja, int wout) {
  __shared__ __align__(16) ushort_t sxu[BT * XPH];
  __shared__ __align__(16) ushort_t swu[KT * WPH];
  __shared__ float sv[BT * SVP];
  const int tid = threadIdx.x;
  const int kc = blockIdx.x & (KCN - 1);
  const int bgi = blockIdx.x >> 5;
  const int b0 = bgi * BT;
  const int k0 = kc * KT;
  {
    const uint4* gx = (const uint4*)Xb + ((size_t)b0 * NK + k0);
    for (int i = tid; i < BT * KT; i += 256) {
      const int b = i / KT, q = i - b * KT;
      *(uint4*)&sxu[b * XPH + q * 8] = gx[(size_t)b * NK + q];
    }
  }
  {
    const uint4* gw = (const uint4*)WTb + ((size_t)ja * NK + k0) * NU;
    for (int i = tid; i < KT * NU; i += 256) {
      const int k = i >> 4, u = i & 15;
      *(uint4*)&swu[k * WPH + u * 8] = gw[i];
    }
  }
  {
    const int b = tid >> 4, u = tid & 15;
    const float s = sprev[(size_t)(b0 + b) * NU + u];
    float sq = s * s;
    sq += __shfl_xor(sq, 1, 64);
    sq += __shfl_xor(sq, 2, 64);
    sq += __shfl_xor(sq, 4, 64);
    sq += __shfl_xor(sq, 8, 64);
    const float scale = (sq / (1.f + sq)) / (sqrtf(sq) + EPSQ);
    const float vv = scale * s;
    sv[b * SVP + u] = vv;
    if (wout && kc == 0) out[((size_t)(b0 + b) * NJ + ja) * NU + u] = vv;
  }
  __syncthreads();
  const int w = tid >> 6;
  const int lane = tid & 63;
  const int kq = lane >> 4;
  const int bq = (lane >> 2) & 3;
  const int uq = lane & 3;
  float4 vf[4];
#pragma unroll
  for (int i = 0; i < 4; ++i)
    vf[i] = *(const float4*)&sv[(bq * 4 + i) * SVP + uq * 4];
#pragma unroll
  for (int it = 0; it < 3; ++it) {
    const int kli = it * 4 + kq;
    if (kli < 9) {
      const int kl = w * 9 + kli;
      float xd[4][8];
#pragma unroll
      for (int i = 0; i < 4; ++i)
        up8(*(const uint4*)&sxu[(bq * 4 + i) * XPH + kl * 8], xd[i]);
      float ag = 0.f;
#pragma unroll
      for (int m = 0; m < 4; ++m) {
        float wd[8];
        up8(*(const uint4*)&swu[kl * WPH + (uq * 4 + m) * 8], wd);
#pragma unroll
        for (int i = 0; i < 4; ++i) {
          const float vm = (m == 0) ? vf[i].x
                         : (m == 1) ? vf[i].y
                         : (m == 2) ? vf[i].z : vf[i].w;
          ag = fmaf(vm, dot8(xd[i], wd), ag);
        }
      }
      ag += __shfl_xor(ag, 1, 64);
      ag += __shfl_xor(ag, 2, 64);
      ag += __shfl_xor(ag, 4, 64);
      ag += __shfl_xor(ag, 8, 64);
      if ((lane & 15) == 0)
        atomicAdd(&bl[(size_t)(k0 + kl) * NJ + ja], ag);
    }
  }
}

__global__ __launch_bounds__(256) void caps_finout(const float* __restrict__ slast,
                                                   float* __restrict__ out) {
  const int g = blockIdx.x * 256 + threadIdx.x;
  const int b = g >> 4, u = g & 15;
  const float s = slast[(size_t)b * NU + u];
  float sq = s * s;
  sq += __shfl_xor(sq, 1, 64);
  sq += __shfl_xor(sq, 2, 64);
  sq += __shfl_xor(sq, 4, 64);
  sq += __shfl_xor(sq, 8, 64);
  const float scale = (sq / (1.f + sq)) / (sqrtf(sq) + EPSQ);
  out[((size_t)b * NJ + (NJ - 1)) * NU + u] = scale * s;
}

// ---------------------------------------------------------------------------
extern "C" void kernel_launch(void* const* d_in, const int* in_sizes, int n_in,
                              void* d_out, int out_size, void* d_ws,
                              size_t ws_size, hipStream_t stream) {
  (void)in_sizes; (void)n_in; (void)out_size; (void)ws_size;
  const float* x = (const float*)d_in[0];   // [512][1152][8][1] fp32
  const float* W = (const float*)d_in[1];   // [10][1152][8][16] fp32
  float* out = (float*)d_out;               // [512][10][16][1] fp32
  float* ws = (float*)d_ws;
  float* bl = ws + OFF_BL;
  float* s  = ws + OFF_S;
  ushort_t* Xb  = (ushort_t*)(ws + OFF_XB);
  ushort_t* WTb = (ushort_t*)(ws + OFF_WTB);
  int* cs = (int*)(ws + OFF_CNT);           // [NPH][BGN]
  int* cb = cs + NPH * BGN;                 // [NPH][KCN]
  float* s_part = ws + OFF_SPART;           // [2][KCN][NB][NU]
  float* ag_part = ws + OFF_AGP;            // [2][BGN][NK]

  caps_init<<<(NB * NK * ND / 8 + 255) / 256, 256, 0, stream>>>(x, W, bl, s,
                                                                Xb, WTb, cs);

  void* args[] = {&Xb, &WTb, &s_part, &ag_part, &out, &cs, &cb};
  hipError_t err = hipLaunchCooperativeKernel(
      (const void*)caps_main, dim3(KCN * BGN), dim3(256), args, 0, stream);

  if (err != hipSuccess) {
    // Fallback: proven 59-launch sequence (identical numerics).
    for (int n = 0; n < NPH; ++n) {
      const int j = n / 3, t = n - 3 * j;
      if (n > 0) {
        const int ja = (t == 0) ? (j - 1) : j;
        caps_agp<<<KCN * BGN, 256, 0, stream>>>(
            Xb, WTb, s + (size_t)(n - 1) * NB * NU, bl, out, ja,
            (t == 0) ? 1 : 0);
      }
      caps_part<<<KCN * BGN, 256, 0, stream>>>(Xb, WTb, bl,
                                               s + (size_t)n * NB * NU, j);
    }
    caps_finout<<<(NB * NU) / 256, 256, 0, stream>>>(
        s + (size_t)(NPH - 1) * NB * NU, out);
  }
}

// Round 6
// 912.015 us; speedup vs baseline: 3.8106x; 3.8106x over previous
//
#include <hip/hip_runtime.h>

typedef unsigned int uint;
typedef unsigned short ushort_t;

#define NB 512      // batch
#define NK 1152     // input capsules
#define ND 8        // in dim
#define NU 16       // out dim
#define NJ 10       // output capsules
#define NPH 30      // routing phases (NJ * 3)
#define EPSQ 1e-7f

#define TPB 512     // threads per fused block (8 waves)
#define BTF 2       // b per fused block
#define BGF (NB / BTF)  // 256 blocks -> ~1 block/CU
#define KPT 3       // max k per thread: ceil(1152/512); tid<128 do 3, rest 2

// ws layout (floats)
#define OFF_BL 0                          // b_logits [NK][NJ]  11520 floats
#define OFF_XB 11520                      // Xb bf16 [NB][NK][ND]
#define OFF_WTB (OFF_XB + (NB*NK*ND)/2)   // WTb bf16 [NJ][NK][NU][ND]
// total ~12.4 MB << ws

// fp32 -> bf16 RNE (values are finite/normal here)
__device__ __forceinline__ ushort_t b16(float f) {
  uint u = __float_as_uint(f);
  return (ushort_t)((u + 0x7fffu + ((u >> 16) & 1u)) >> 16);
}
// unpack 8 bf16 (uint4) -> 8 fp32
__device__ __forceinline__ void up8(const uint4 v, float* f) {
  f[0] = __uint_as_float(v.x << 16); f[1] = __uint_as_float(v.x & 0xffff0000u);
  f[2] = __uint_as_float(v.y << 16); f[3] = __uint_as_float(v.y & 0xffff0000u);
  f[4] = __uint_as_float(v.z << 16); f[5] = __uint_as_float(v.z & 0xffff0000u);
  f[6] = __uint_as_float(v.w << 16); f[7] = __uint_as_float(v.w & 0xffff0000u);
}
__device__ __forceinline__ float dot8(const float* a, const float* b) {
  return a[0]*b[0] + a[1]*b[1] + a[2]*b[2] + a[3]*b[3] +
         a[4]*b[4] + a[5]*b[5] + a[6]*b[6] + a[7]*b[7];
}

// ---------------------------------------------------------------------------
// init: zero bl; build Xb[b][k][d] (bf16) and WTb[j][k][u][d] (bf16)
// ---------------------------------------------------------------------------
__global__ __launch_bounds__(256) void caps_init(const float* __restrict__ x,
                                                 const float* __restrict__ W,
                                                 float* __restrict__ bl,
                                                 ushort_t* __restrict__ Xb,
                                                 ushort_t* __restrict__ WTb) {
  const int g = blockIdx.x * 256 + threadIdx.x;
  if (g < NK * NJ) bl[g] = 0.f;
  if (g < (NB * NK * ND) / 8) {  // 589824 groups of 8
    const float4* xp = (const float4*)x + (size_t)g * 2;
    const float4 a = xp[0], b = xp[1];
    uint4 o;
    o.x = (uint)b16(a.x) | ((uint)b16(a.y) << 16);
    o.y = (uint)b16(a.z) | ((uint)b16(a.w) << 16);
    o.z = (uint)b16(b.x) | ((uint)b16(b.y) << 16);
    o.w = (uint)b16(b.z) | ((uint)b16(b.w) << 16);
    ((uint4*)Xb)[g] = o;
  }
  if (g < (NJ * NK * NU * ND) / 8) {  // 184320 groups: (j,k,u) rows of 8 d
    const int u = g & 15;
    const int k = (g >> 4) % NK;
    const int j = g / (NK * NU);
    const float* wp = W + ((size_t)(j * NK + k) * ND) * NU + u;  // d-stride NU
    uint4 o;
    o.x = (uint)b16(wp[0])  | ((uint)b16(wp[16]) << 16);
    o.y = (uint)b16(wp[32]) | ((uint)b16(wp[48]) << 16);
    o.z = (uint)b16(wp[64]) | ((uint)b16(wp[80]) << 16);
    o.w = (uint)b16(wp[96]) | ((uint)b16(wp[112]) << 16);
    ((uint4*)WTb)[g] = o;
  }
}

// ---------------------------------------------------------------------------
// caps_fused: ONE launch per routing phase (halves the 59-launch baseline's
// sync count). Block owns BTF=2 batches x ALL 1152 k -> the s-reduction is
// fully intra-block (shuffle+LDS); only the bl update crosses blocks
// (atomicAdd + launch boundary, exactly the proven baseline semantics).
// Thread t owns k in {t, t+512, t+1024}. uh kept in registers between the
// s-pass and the agree-pass, so W is read from L2 only once per block.
// Phase n=(j,t): softmax(bl, col j) -> s (intra-block reduce) -> squash
// [-> out if t==2] -> agree: atomicAdd bl[k][j]  (skipped at n==29, dead).
// ---------------------------------------------------------------------------
__global__ __launch_bounds__(TPB, 2) void caps_fused(
    const ushort_t* __restrict__ Xb, const ushort_t* __restrict__ WTb,
    float* __restrict__ bl, float* __restrict__ out,
    int j, int writeOut, int doAgree) {
  __shared__ float c_lds[NK];                 // 4608 B softmax coefficients
  __shared__ float sred[8][BTF][NU];          // 1024 B cross-wave s partials
  __shared__ float sv[BTF][NU];               // 128 B  squashed v
  const int tid = threadIdx.x;
  const int lane = tid & 63;
  const int w = tid >> 6;
  const int b0 = blockIdx.x * BTF;

  // --- softmax coefficient c_k for column j, all k (block-redundant, cheap)
  for (int k = tid; k < NK; k += TPB) {
    const float* row = bl + (size_t)k * NJ;   // prev launches' atomicAdds
    float r[NJ];                               // visible across boundary
#pragma unroll
    for (int jj = 0; jj < NJ; ++jj) r[jj] = row[jj];
    float mx = r[0];
#pragma unroll
    for (int jj = 1; jj < NJ; ++jj) mx = fmaxf(mx, r[jj]);
    float se = 0.f;
#pragma unroll
    for (int jj = 0; jj < NJ; ++jj) se += __expf(r[jj] - mx);
    c_lds[k] = __expf(r[j] - mx) / se;
  }
  __syncthreads();

  // --- pass 1: uh[k,b,u] (kept in regs) and weighted partial s
  float uh[KPT][BTF][NU];                     // 96 VGPR
  float s0[NU], s1[NU];
#pragma unroll
  for (int u = 0; u < NU; ++u) { s0[u] = 0.f; s1[u] = 0.f; }
#pragma unroll
  for (int i = 0; i < KPT; ++i) {
    const int k = tid + i * TPB;
    if (k < NK) {
      const float ck = c_lds[k];
      float xd0[8], xd1[8];
      up8(((const uint4*)Xb)[(size_t)b0 * NK + k], xd0);
      up8(((const uint4*)Xb)[(size_t)(b0 + 1) * NK + k], xd1);
      const uint4* wrow = (const uint4*)WTb + ((size_t)j * NK + k) * NU;
#pragma unroll
      for (int u = 0; u < NU; ++u) {
        float wd[8];
        up8(wrow[u], wd);
        const float h0 = dot8(xd0, wd);
        const float h1 = dot8(xd1, wd);
        uh[i][0][u] = h0; uh[i][1][u] = h1;
        s0[u] = fmaf(ck, h0, s0[u]);
        s1[u] = fmaf(ck, h1, s1[u]);
      }
    } else {
#pragma unroll
      for (int u = 0; u < NU; ++u) { uh[i][0][u] = 0.f; uh[i][1][u] = 0.f; }
    }
  }
  // wave-level butterfly: each wave sums its 64 threads' partials
#pragma unroll
  for (int u = 0; u < NU; ++u) {
#pragma unroll
    for (int off = 1; off < 64; off <<= 1) {
      s0[u] += __shfl_xor(s0[u], off, 64);
      s1[u] += __shfl_xor(s1[u], off, 64);
    }
  }
  if (lane == 0) {
#pragma unroll
    for (int u = 0; u < NU; ++u) {
      sred[w][0][u] = s0[u];
      sred[w][1][u] = s1[u];
    }
  }
  __syncthreads();

  // --- fold 8 waves + squash (tid < 32: lanes 0-15 = b0, 16-31 = b0+1)
  if (tid < BTF * NU) {
    const int b = tid >> 4, u = tid & 15;
    float sval = 0.f;
#pragma unroll
    for (int wv = 0; wv < 8; ++wv) sval += sred[wv][b][u];
    float sq = sval * sval;
    sq += __shfl_xor(sq, 1, 64);
    sq += __shfl_xor(sq, 2, 64);
    sq += __shfl_xor(sq, 4, 64);
    sq += __shfl_xor(sq, 8, 64);   // stays within each 16-lane b-group
    const float scale = (sq / (1.f + sq)) / (sqrtf(sq) + EPSQ);
    const float vv = scale * sval;
    sv[b][u] = vv;
    if (writeOut)
      out[((size_t)(b0 + b) * NJ + j) * NU + u] = vv;
  }
  __syncthreads();

  // --- pass 2: agreement from cached uh (no W re-read)
  if (doAgree) {
    float v0[NU], v1[NU];
#pragma unroll
    for (int u = 0; u < NU; ++u) { v0[u] = sv[0][u]; v1[u] = sv[1][u]; }
#pragma unroll
    for (int i = 0; i < KPT; ++i) {
      const int k = tid + i * TPB;
      if (k < NK) {
        float ag = 0.f;
#pragma unroll
        for (int u = 0; u < NU; ++u)
          ag += uh[i][0][u] * v0[u] + uh[i][1][u] * v1[u];
        // 256 adders per address (one per block), addresses distinct per
        // lane within a wave -> conflict-free issue; baseline proved the
        // atomicAdd+launch-boundary pattern at 32-way.
        atomicAdd(&bl[(size_t)k * NJ + j], ag);
      }
    }
  }
}

// ---------------------------------------------------------------------------
extern "C" void kernel_launch(void* const* d_in, const int* in_sizes, int n_in,
                              void* d_out, int out_size, void* d_ws,
                              size_t ws_size, hipStream_t stream) {
  (void)in_sizes; (void)n_in; (void)out_size; (void)ws_size;
  const float* x = (const float*)d_in[0];   // [512][1152][8][1] fp32
  const float* W = (const float*)d_in[1];   // [10][1152][8][16] fp32
  float* out = (float*)d_out;               // [512][10][16][1] fp32
  float* ws = (float*)d_ws;
  float* bl = ws + OFF_BL;
  ushort_t* Xb  = (ushort_t*)(ws + OFF_XB);
  ushort_t* WTb = (ushort_t*)(ws + OFF_WTB);

  caps_init<<<(NB * NK * ND / 8 + 255) / 256, 256, 0, stream>>>(x, W, bl, Xb,
                                                                WTb);
  for (int n = 0; n < NPH; ++n) {
    const int j = n / 3;
    const int t = n - 3 * j;
    caps_fused<<<BGF, TPB, 0, stream>>>(Xb, WTb, bl, out, j,
                                        (t == 2) ? 1 : 0,
                                        (n < NPH - 1) ? 1 : 0);
  }
}

// Round 7
// 820.395 us; speedup vs baseline: 4.2362x; 1.1117x over previous
//
#include <hip/hip_runtime.h>

typedef unsigned int uint;
typedef unsigned short ushort_t;

#define NB 512      // batch
#define NK 1152     // input capsules
#define ND 8        // in dim
#define NU 16       // out dim
#define NJ 10       // output capsules
#define NPH 30      // routing phases (NJ * 3)
#define EPSQ 1e-7f

#define TPB 512     // threads per fused block (8 waves)
#define BTF 2       // b per fused block
#define BGF (NB / BTF)  // 256 blocks -> ~1 block/CU
#define KPT 3       // max k per thread: ceil(1152/512); tid<128 do 3, rest 2

// ws layout (floats)
#define OFF_BL 0                          // b_logits [NK][NJ]  11520 floats
#define OFF_XB 11520                      // Xb bf16 [NB][NK][ND]
#define OFF_WTB (OFF_XB + (NB*NK*ND)/2)   // WTb bf16 [NJ][NU][NK][ND]  (TRANSPOSED)
// total ~12.4 MB << ws

// fp32 -> bf16 RNE (values are finite/normal here)
__device__ __forceinline__ ushort_t b16(float f) {
  uint u = __float_as_uint(f);
  return (ushort_t)((u + 0x7fffu + ((u >> 16) & 1u)) >> 16);
}
// unpack 8 bf16 (uint4) -> 8 fp32
__device__ __forceinline__ void up8(const uint4 v, float* f) {
  f[0] = __uint_as_float(v.x << 16); f[1] = __uint_as_float(v.x & 0xffff0000u);
  f[2] = __uint_as_float(v.y << 16); f[3] = __uint_as_float(v.y & 0xffff0000u);
  f[4] = __uint_as_float(v.z << 16); f[5] = __uint_as_float(v.z & 0xffff0000u);
  f[6] = __uint_as_float(v.w << 16); f[7] = __uint_as_float(v.w & 0xffff0000u);
}
__device__ __forceinline__ float dot8(const float* a, const float* b) {
  return a[0]*b[0] + a[1]*b[1] + a[2]*b[2] + a[3]*b[3] +
         a[4]*b[4] + a[5]*b[5] + a[6]*b[6] + a[7]*b[7];
}

// ---------------------------------------------------------------------------
// init: zero bl; build Xb[b][k][d] (bf16) and WTb[j][u][k][d] (bf16).
// W layout is TRANSPOSED (u-major over k) so caps_fused's per-u load is
// coalesced: lane t reads k=t -> consecutive 16B -> one 1024B transaction.
// (Round-6 layout [j][k][u][d] made every W load a 64-line gather: lane t's
// 16B at stride 256B. With 2 waves/SIMD there was nothing to hide it.)
// ---------------------------------------------------------------------------
__global__ __launch_bounds__(256) void caps_init(const float* __restrict__ x,
                                                 const float* __restrict__ W,
                                                 float* __restrict__ bl,
                                                 ushort_t* __restrict__ Xb,
                                                 ushort_t* __restrict__ WTb) {
  const int g = blockIdx.x * 256 + threadIdx.x;
  if (g < NK * NJ) bl[g] = 0.f;
  if (g < (NB * NK * ND) / 8) {  // 589824 groups of 8
    const float4* xp = (const float4*)x + (size_t)g * 2;
    const float4 a = xp[0], b = xp[1];
    uint4 o;
    o.x = (uint)b16(a.x) | ((uint)b16(a.y) << 16);
    o.y = (uint)b16(a.z) | ((uint)b16(a.w) << 16);
    o.z = (uint)b16(b.x) | ((uint)b16(b.y) << 16);
    o.w = (uint)b16(b.z) | ((uint)b16(b.w) << 16);
    ((uint4*)Xb)[g] = o;
  }
  if (g < (NJ * NK * NU * ND) / 8) {  // 184320 groups: g = ((j*NU)+u)*NK + k
    const int k = g % NK;
    const int u = (g / NK) % NU;
    const int j = g / (NK * NU);
    const float* wp = W + ((size_t)(j * NK + k) * ND) * NU + u;  // d-stride NU
    uint4 o;
    o.x = (uint)b16(wp[0])  | ((uint)b16(wp[16]) << 16);
    o.y = (uint)b16(wp[32]) | ((uint)b16(wp[48]) << 16);
    o.z = (uint)b16(wp[64]) | ((uint)b16(wp[80]) << 16);
    o.w = (uint)b16(wp[96]) | ((uint)b16(wp[112]) << 16);
    ((uint4*)WTb)[g] = o;  // [j][u][k] row of 8 d's
  }
}

// ---------------------------------------------------------------------------
// caps_fused: ONE launch per routing phase. Block owns BTF=2 batches x ALL
// 1152 k -> s-reduction is intra-block (shuffle+LDS); only the bl update
// crosses blocks (atomicAdd + launch boundary = proven baseline semantics).
// Thread t owns k in {t, t+512, t+1024}. uh kept in registers between the
// s-pass and the agree-pass, so W is read from L2 only once per block.
// All global loads coalesced (X: lane-consecutive uint4; W: [j][u][k] plane).
// ---------------------------------------------------------------------------
__global__ __launch_bounds__(TPB, 2) void caps_fused(
    const ushort_t* __restrict__ Xb, const ushort_t* __restrict__ WTb,
    float* __restrict__ bl, float* __restrict__ out,
    int j, int writeOut, int doAgree) {
  __shared__ float c_lds[NK];                 // 4608 B softmax coefficients
  __shared__ float sred[8][BTF][NU];          // 1024 B cross-wave s partials
  __shared__ float sv[BTF][NU];               // 128 B  squashed v
  const int tid = threadIdx.x;
  const int lane = tid & 63;
  const int w = tid >> 6;
  const int b0 = blockIdx.x * BTF;

  // --- softmax coefficient c_k for column j, all k (block-redundant, cheap)
  for (int k = tid; k < NK; k += TPB) {
    const float* row = bl + (size_t)k * NJ;   // prev launches' atomicAdds
    float r[NJ];                               // visible across boundary
#pragma unroll
    for (int jj = 0; jj < NJ; ++jj) r[jj] = row[jj];
    float mx = r[0];
#pragma unroll
    for (int jj = 1; jj < NJ; ++jj) mx = fmaxf(mx, r[jj]);
    float se = 0.f;
#pragma unroll
    for (int jj = 0; jj < NJ; ++jj) se += __expf(r[jj] - mx);
    c_lds[k] = __expf(r[j] - mx) / se;
  }
  __syncthreads();

  // --- pass 1: uh[k,b,u] (kept in regs) and weighted partial s
  const uint4* wplane = (const uint4*)WTb + (size_t)j * NU * NK;
  float uh[KPT][BTF][NU];                     // 96 VGPR
  float s0[NU], s1[NU];
#pragma unroll
  for (int u = 0; u < NU; ++u) { s0[u] = 0.f; s1[u] = 0.f; }
#pragma unroll
  for (int i = 0; i < KPT; ++i) {
    const int k = tid + i * TPB;
    if (k < NK) {
      const float ck = c_lds[k];
      float xd0[8], xd1[8];
      up8(((const uint4*)Xb)[(size_t)b0 * NK + k], xd0);
      up8(((const uint4*)Xb)[(size_t)(b0 + 1) * NK + k], xd1);
#pragma unroll
      for (int u = 0; u < NU; ++u) {
        float wd[8];
        up8(wplane[(size_t)u * NK + k], wd);   // coalesced: lane t -> k=t
        const float h0 = dot8(xd0, wd);
        const float h1 = dot8(xd1, wd);
        uh[i][0][u] = h0; uh[i][1][u] = h1;
        s0[u] = fmaf(ck, h0, s0[u]);
        s1[u] = fmaf(ck, h1, s1[u]);
      }
    } else {
#pragma unroll
      for (int u = 0; u < NU; ++u) { uh[i][0][u] = 0.f; uh[i][1][u] = 0.f; }
    }
  }
  // wave-level butterfly: each wave sums its 64 threads' partials
#pragma unroll
  for (int u = 0; u < NU; ++u) {
#pragma unroll
    for (int off = 1; off < 64; off <<= 1) {
      s0[u] += __shfl_xor(s0[u], off, 64);
      s1[u] += __shfl_xor(s1[u], off, 64);
    }
  }
  if (lane == 0) {
#pragma unroll
    for (int u = 0; u < NU; ++u) {
      sred[w][0][u] = s0[u];
      sred[w][1][u] = s1[u];
    }
  }
  __syncthreads();

  // --- fold 8 waves + squash (tid < 32: lanes 0-15 = b0, 16-31 = b0+1)
  if (tid < BTF * NU) {
    const int b = tid >> 4, u = tid & 15;
    float sval = 0.f;
#pragma unroll
    for (int wv = 0; wv < 8; ++wv) sval += sred[wv][b][u];
    float sq = sval * sval;
    sq += __shfl_xor(sq, 1, 64);
    sq += __shfl_xor(sq, 2, 64);
    sq += __shfl_xor(sq, 4, 64);
    sq += __shfl_xor(sq, 8, 64);   // stays within each 16-lane b-group
    const float scale = (sq / (1.f + sq)) / (sqrtf(sq) + EPSQ);
    const float vv = scale * sval;
    sv[b][u] = vv;
    if (writeOut)
      out[((size_t)(b0 + b) * NJ + j) * NU + u] = vv;
  }
  __syncthreads();

  // --- pass 2: agreement from cached uh (no W re-read)
  if (doAgree) {
    float v0[NU], v1[NU];
#pragma unroll
    for (int u = 0; u < NU; ++u) { v0[u] = sv[0][u]; v1[u] = sv[1][u]; }
#pragma unroll
    for (int i = 0; i < KPT; ++i) {
      const int k = tid + i * TPB;
      if (k < NK) {
        float ag = 0.f;
#pragma unroll
        for (int u = 0; u < NU; ++u)
          ag += uh[i][0][u] * v0[u] + uh[i][1][u] * v1[u];
        // 256 adders per address (one per block); addresses distinct per
        // lane within a wave -> conflict-free issue; native f32 atomic.
        atomicAdd(&bl[(size_t)k * NJ + j], ag);
      }
    }
  }
}

// ---------------------------------------------------------------------------
extern "C" void kernel_launch(void* const* d_in, const int* in_sizes, int n_in,
                              void* d_out, int out_size, void* d_ws,
                              size_t ws_size, hipStream_t stream) {
  (void)in_sizes; (void)n_in; (void)out_size; (void)ws_size;
  const float* x = (const float*)d_in[0];   // [512][1152][8][1] fp32
  const float* W = (const float*)d_in[1];   // [10][1152][8][16] fp32
  float* out = (float*)d_out;               // [512][10][16][1] fp32
  float* ws = (float*)d_ws;
  float* bl = ws + OFF_BL;
  ushort_t* Xb  = (ushort_t*)(ws + OFF_XB);
  ushort_t* WTb = (ushort_t*)(ws + OFF_WTB);

  caps_init<<<(NB * NK * ND / 8 + 255) / 256, 256, 0, stream>>>(x, W, bl, Xb,
                                                                WTb);
  for (int n = 0; n < NPH; ++n) {
    const int j = n / 3;
    const int t = n - 3 * j;
    caps_fused<<<BGF, TPB, 0, stream>>>(Xb, WTb, bl, out, j,
                                        (t == 2) ? 1 : 0,
                                        (n < NPH - 1) ? 1 : 0);
  }
}